// Round 1
// baseline (31.294 us; speedup 1.0000x reference)
//
#include <hip/hip_runtime.h>

// out[b,c,v] = valid ? means[b,idx,c] + stds[b,idx,c] * noise[b,c,v] : 0
// idx = searchsorted(gen_labels, labels[b,v]) clipped; valid = gen_labels[idx]==lab
//
// Memory-bound streaming kernel: vec4 labels + vec4 noise + vec4 out,
// tables (gen_labels, means, stds) cached in LDS.

__device__ __forceinline__ int searchsorted_left(const int* __restrict__ g, int L, int x) {
    int lo = 0, hi = L;
    while (lo < hi) {
        int mid = (lo + hi) >> 1;
        if (g[mid] < x) lo = mid + 1; else hi = mid;
    }
    return lo;
}

__global__ __launch_bounds__(256) void gmm_sample_kernel(
    const int*   __restrict__ labels,   // [B, V]
    const float* __restrict__ means,    // [B, L, C]
    const float* __restrict__ stds,     // [B, L, C]
    const float* __restrict__ noise,    // [B, C, V]
    const int*   __restrict__ gen_labels, // [L]
    float*       __restrict__ out,      // [B, C, V]
    int B, int L, int C, int V)
{
    extern __shared__ char smem_raw[];
    int*   sgl = (int*)smem_raw;          // [L]
    float* sm  = (float*)(sgl + L);       // [B*L*C]
    float* ss  = sm + B * L * C;          // [B*L*C]

    const int BLC = B * L * C;
    for (int i = threadIdx.x; i < L;   i += blockDim.x) sgl[i] = gen_labels[i];
    for (int i = threadIdx.x; i < BLC; i += blockDim.x) { sm[i] = means[i]; ss[i] = stds[i]; }
    __syncthreads();

    const int NV4   = V >> 2;           // vec4 groups per (b)
    const int total = B * NV4;
    const int stride = gridDim.x * blockDim.x;

    for (int g = blockIdx.x * blockDim.x + threadIdx.x; g < total; g += stride) {
        const int b  = g / NV4;
        const int v4 = g - b * NV4;

        const int4 lab = ((const int4*)labels)[b * NV4 + v4];
        const int labv[4] = {lab.x, lab.y, lab.z, lab.w};

        int  idx[4];
        bool val[4];
#pragma unroll
        for (int j = 0; j < 4; ++j) {
            int lo = searchsorted_left(sgl, L, labv[j]);
            int ix = lo < (L - 1) ? lo : (L - 1);
            idx[j] = ix;
            val[j] = (sgl[ix] == labv[j]);
        }

        for (int c = 0; c < C; ++c) {
            const int plane = (b * C + c) * NV4 + v4;
            const float4 nz = ((const float4*)noise)[plane];
            const float nv[4] = {nz.x, nz.y, nz.z, nz.w};
            float ov[4];
#pragma unroll
            for (int j = 0; j < 4; ++j) {
                const int t = (b * L + idx[j]) * C + c;
                ov[j] = val[j] ? fmaf(ss[t], nv[j], sm[t]) : 0.0f;
            }
            float4 o = make_float4(ov[0], ov[1], ov[2], ov[3]);
            ((float4*)out)[plane] = o;
        }
    }
}

// Scalar tail kernel for V not divisible by 4 (not hit for 160^3, kept for correctness).
__global__ void gmm_sample_tail_kernel(
    const int*   __restrict__ labels,
    const float* __restrict__ means,
    const float* __restrict__ stds,
    const float* __restrict__ noise,
    const int*   __restrict__ gen_labels,
    float*       __restrict__ out,
    int B, int L, int C, int V, int vstart)
{
    const int tail   = V - vstart;
    const int total  = B * tail;
    const int stride = gridDim.x * blockDim.x;
    for (int g = blockIdx.x * blockDim.x + threadIdx.x; g < total; g += stride) {
        const int b = g / tail;
        const int v = vstart + (g - b * tail);
        const int labv = labels[b * V + v];
        int lo = 0, hi = L;
        while (lo < hi) { int mid = (lo + hi) >> 1; if (gen_labels[mid] < labv) lo = mid + 1; else hi = mid; }
        int ix = lo < (L - 1) ? lo : (L - 1);
        bool valid = (gen_labels[ix] == labv);
        for (int c = 0; c < C; ++c) {
            const int t = (b * L + ix) * C + c;
            const long long p = (long long)(b * C + c) * V + v;
            out[p] = valid ? fmaf(stds[t], noise[p], means[t]) : 0.0f;
        }
    }
}

extern "C" void kernel_launch(void* const* d_in, const int* in_sizes, int n_in,
                              void* d_out, int out_size, void* d_ws, size_t ws_size,
                              hipStream_t stream) {
    const int*   labels = (const int*)  d_in[0];
    const float* means  = (const float*)d_in[1];
    const float* stds   = (const float*)d_in[2];
    const float* noise  = (const float*)d_in[3];
    const int*   gl     = (const int*)  d_in[4];
    float*       out    = (float*)      d_out;

    const int L   = in_sizes[4];                 // 20
    const int C   = in_sizes[3] / in_sizes[0];   // (B*C*V)/(B*V) = 2
    const int B   = in_sizes[1] / (L * C);       // 2
    const int V   = in_sizes[0] / B;             // 160^3

    const int NV4   = V >> 2;
    const int total = B * NV4;
    const int block = 256;
    int grid = (total + block - 1) / block;
    if (grid > 2048) grid = 2048;
    if (grid < 1) grid = 1;

    const size_t smem = (size_t)L * sizeof(int) + 2ull * B * L * C * sizeof(float);

    gmm_sample_kernel<<<grid, block, smem, stream>>>(
        labels, means, stds, noise, gl, out, B, L, C, V);

    const int vstart = NV4 << 2;
    if (vstart < V) {
        const int tail_total = B * (V - vstart);
        int tgrid = (tail_total + block - 1) / block;
        if (tgrid > 256) tgrid = 256;
        gmm_sample_tail_kernel<<<tgrid, block, 0, stream>>>(
            labels, means, stds, noise, gl, out, B, L, C, V, vstart);
    }
}

// Round 2
// 30.719 us; speedup vs baseline: 1.0187x; 1.0187x over previous
//
#include <hip/hip_runtime.h>

// out[b,c,v] = valid ? means[b,idx,c] + stds[b,idx,c] * noise[b,c,v] : 0
// idx = searchsorted(gen_labels, labels[b,v]) clipped; valid = gen_labels[idx]==lab
//
// Latency-optimized: on-device detection of gen_labels == arange (the actual
// data) turns the searchsorted into 2 VALU ops. Fused float4 LDS table for
// C==2 (one ds_read_b128 per label serves both channels). Non-temporal output
// stores keep inputs L3-resident. Binary-search fallback for general inputs.

typedef float f32x4 __attribute__((ext_vector_type(4)));

__device__ __forceinline__ int searchsorted_left(const int* __restrict__ g, int L, int x) {
    int lo = 0, hi = L;
    while (lo < hi) {
        int mid = (lo + hi) >> 1;
        if (g[mid] < x) lo = mid + 1; else hi = mid;
    }
    return lo;
}

__global__ __launch_bounds__(256) void gmm_fast_kernel(
    const int*   __restrict__ labels,     // [B, V]
    const float* __restrict__ means,      // [B, L, C]
    const float* __restrict__ stds,       // [B, L, C]
    const float* __restrict__ noise,      // [B, C, V]
    const int*   __restrict__ gen_labels, // [L]
    float*       __restrict__ out,        // [B, C, V]
    int B, int L, int C, int V)
{
    const int b = blockIdx.y;

    extern __shared__ char smem_raw[];
    int*  sgl   = (int*)smem_raw;                       // [L]
    char* after = (char*)(sgl + ((L + 3) & ~3));        // 16B-align
    f32x4* tbl  = (f32x4*)after;                        // [L] (m0,m1,s0,s1)  (C==2 path)
    float* smn  = (float*)after;                        // [L*C]              (generic path)
    float* ssd  = smn + L * C;                          // [L*C]

    for (int i = threadIdx.x; i < L; i += blockDim.x) sgl[i] = gen_labels[i];
    if (C == 2) {
        for (int i = threadIdx.x; i < L; i += blockDim.x) {
            const float* mp = means + ((long long)b * L + i) * 2;
            const float* sp = stds  + ((long long)b * L + i) * 2;
            f32x4 t; t.x = mp[0]; t.y = mp[1]; t.z = sp[0]; t.w = sp[1];
            tbl[i] = t;
        }
    } else {
        const long long base = (long long)b * L * C;
        for (int i = threadIdx.x; i < L * C; i += blockDim.x) {
            smn[i] = means[base + i];
            ssd[i] = stds[base + i];
        }
    }
    __syncthreads();

    // Uniform fast-path detection: gen_labels == g0 + i (arithmetic range).
    const int g0 = sgl[0];
    bool ar = true;
    for (int i = 1; i < L; ++i) ar = ar && (sgl[i] == g0 + i);

    const int NV4 = V >> 2;
    const unsigned uL = (unsigned)L;
    const int4* lab4 = (const int4*)(labels + (long long)b * V);

    if (ar && C == 2) {
        const f32x4* nz0 = (const f32x4*)(noise + (long long)(b * C + 0) * V);
        const f32x4* nz1 = (const f32x4*)(noise + (long long)(b * C + 1) * V);
        f32x4* o0 = (f32x4*)(out + (long long)(b * C + 0) * V);
        f32x4* o1 = (f32x4*)(out + (long long)(b * C + 1) * V);
        const int step = blockDim.x * 2;
        for (int base = blockIdx.x * step; base < NV4; base += gridDim.x * step) {
#pragma unroll
            for (int h = 0; h < 2; ++h) {
                const int i0 = base + h * blockDim.x + threadIdx.x;
                if (i0 >= NV4) continue;
                const int4 la = lab4[i0];
                const int lv[4] = {la.x, la.y, la.z, la.w};
                f32x4 t[4];
                bool  val[4];
#pragma unroll
                for (int j = 0; j < 4; ++j) {
                    const unsigned d = (unsigned)(lv[j] - g0);
                    val[j] = d < uL;
                    const unsigned ix = val[j] ? d : (uL - 1u);
                    t[j] = tbl[ix];                      // ds_read_b128
                }
                const f32x4 na = nz0[i0];
                const f32x4 nb = nz1[i0];
                f32x4 oa, ob;
                oa.x = val[0] ? fmaf(t[0].z, na.x, t[0].x) : 0.f;
                oa.y = val[1] ? fmaf(t[1].z, na.y, t[1].x) : 0.f;
                oa.z = val[2] ? fmaf(t[2].z, na.z, t[2].x) : 0.f;
                oa.w = val[3] ? fmaf(t[3].z, na.w, t[3].x) : 0.f;
                ob.x = val[0] ? fmaf(t[0].w, nb.x, t[0].y) : 0.f;
                ob.y = val[1] ? fmaf(t[1].w, nb.y, t[1].y) : 0.f;
                ob.z = val[2] ? fmaf(t[2].w, nb.z, t[2].y) : 0.f;
                ob.w = val[3] ? fmaf(t[3].w, nb.w, t[3].y) : 0.f;
                __builtin_nontemporal_store(oa, &o0[i0]);
                __builtin_nontemporal_store(ob, &o1[i0]);
            }
        }
    } else {
        // Generic fallback: LDS binary search + per-channel tables.
        const int step = blockDim.x * 2;
        for (int base = blockIdx.x * step; base < NV4; base += gridDim.x * step) {
#pragma unroll
            for (int h = 0; h < 2; ++h) {
                const int i0 = base + h * blockDim.x + threadIdx.x;
                if (i0 >= NV4) continue;
                const int4 la = lab4[i0];
                const int lv[4] = {la.x, la.y, la.z, la.w};
                int  idx[4]; bool val[4];
#pragma unroll
                for (int j = 0; j < 4; ++j) {
                    int lo = searchsorted_left(sgl, L, lv[j]);
                    int ix = lo < (L - 1) ? lo : (L - 1);
                    idx[j] = ix;
                    val[j] = (sgl[ix] == lv[j]);
                }
                for (int c = 0; c < C; ++c) {
                    const long long plane = ((long long)(b * C + c) * V) >> 2;
                    const float4 nzv = ((const float4*)noise)[plane + i0];
                    const float nv[4] = {nzv.x, nzv.y, nzv.z, nzv.w};
                    f32x4 o;
#pragma unroll
                    for (int j = 0; j < 4; ++j) {
                        const int t = idx[j] * C + c;
                        float r = val[j] ? fmaf(ssd[t], nv[j], smn[t]) : 0.f;
                        if (j == 0) o.x = r; else if (j == 1) o.y = r;
                        else if (j == 2) o.z = r; else o.w = r;
                    }
                    __builtin_nontemporal_store(o, (f32x4*)out + plane + i0);
                }
            }
        }
    }
}

// Scalar tail for V % 4 != 0 (not hit for 160^3).
__global__ void gmm_sample_tail_kernel(
    const int*   __restrict__ labels,
    const float* __restrict__ means,
    const float* __restrict__ stds,
    const float* __restrict__ noise,
    const int*   __restrict__ gen_labels,
    float*       __restrict__ out,
    int B, int L, int C, int V, int vstart)
{
    const int tail   = V - vstart;
    const int total  = B * tail;
    const int stride = gridDim.x * blockDim.x;
    for (int g = blockIdx.x * blockDim.x + threadIdx.x; g < total; g += stride) {
        const int b = g / tail;
        const int v = vstart + (g - b * tail);
        const int labv = labels[(long long)b * V + v];
        int lo = 0, hi = L;
        while (lo < hi) { int mid = (lo + hi) >> 1; if (gen_labels[mid] < labv) lo = mid + 1; else hi = mid; }
        int ix = lo < (L - 1) ? lo : (L - 1);
        bool valid = (gen_labels[ix] == labv);
        for (int c = 0; c < C; ++c) {
            const int t = (b * L + ix) * C + c;
            const long long p = (long long)(b * C + c) * V + v;
            out[p] = valid ? fmaf(stds[t], noise[p], means[t]) : 0.0f;
        }
    }
}

extern "C" void kernel_launch(void* const* d_in, const int* in_sizes, int n_in,
                              void* d_out, int out_size, void* d_ws, size_t ws_size,
                              hipStream_t stream) {
    const int*   labels = (const int*)  d_in[0];
    const float* means  = (const float*)d_in[1];
    const float* stds   = (const float*)d_in[2];
    const float* noise  = (const float*)d_in[3];
    const int*   gl     = (const int*)  d_in[4];
    float*       out    = (float*)      d_out;

    const int L = in_sizes[4];                 // 20
    const int C = in_sizes[3] / in_sizes[0];   // 2
    const int B = in_sizes[1] / (L * C);       // 2
    const int V = in_sizes[0] / B;             // 160^3

    const int NV4  = V >> 2;
    const int block = 256;
    const int per_block = block * 2;           // vec4 groups per block per trip
    int gx = (NV4 + per_block - 1) / per_block;
    if (gx > 1024) gx = 1024;
    if (gx < 1) gx = 1;
    dim3 grid(gx, B);

    size_t tblBytes = (size_t)L * 16;
    size_t genBytes = 2ull * L * C * sizeof(float);
    size_t smem = (size_t)((L + 3) & ~3) * sizeof(int) +
                  (tblBytes > genBytes ? tblBytes : genBytes);

    gmm_fast_kernel<<<grid, block, smem, stream>>>(
        labels, means, stds, noise, gl, out, B, L, C, V);

    const int vstart = NV4 << 2;
    if (vstart < V) {
        const int tail_total = B * (V - vstart);
        int tgrid = (tail_total + block - 1) / block;
        if (tgrid > 256) tgrid = 256;
        gmm_sample_tail_kernel<<<tgrid, block, 0, stream>>>(
            labels, means, stds, noise, gl, out, B, L, C, V, vstart);
    }
}

// Round 3
// 30.429 us; speedup vs baseline: 1.0284x; 1.0095x over previous
//
#include <hip/hip_runtime.h>

// out[b,c,v] = valid ? means[b,idx,c] + stds[b,idx,c] * noise[b,c,v] : 0
// idx = searchsorted(gen_labels, labels[b,v]); valid = gen_labels[idx]==lab
//
// R3: latency-bound fix — exact-fit grid, 4 vec4-groups per thread, all 12
// global loads issued before any consumer (12 VMEM in flight/wave). Arange
// fast path (idx = lab-g0) + fused float4 LDS table for C==2. Fallback
// flexible kernel for non-exact shapes / generic gen_labels.

typedef float f32x4 __attribute__((ext_vector_type(4)));

#define TGROUPS 4

__device__ __forceinline__ int searchsorted_left(const int* __restrict__ g, int L, int x) {
    int lo = 0, hi = L;
    while (lo < hi) {
        int mid = (lo + hi) >> 1;
        if (g[mid] < x) lo = mid + 1; else hi = mid;
    }
    return lo;
}

// ---------------- exact-fit kernel: NV4 == gridDim.x * 256 * TGROUPS ----------
__global__ __launch_bounds__(256) void gmm_exact_kernel(
    const int*   __restrict__ labels,     // [B, V]
    const float* __restrict__ means,      // [B, L, C]
    const float* __restrict__ stds,       // [B, L, C]
    const float* __restrict__ noise,      // [B, C, V]
    const int*   __restrict__ gen_labels, // [L]
    float*       __restrict__ out,        // [B, C, V]
    int L, int C, int V)
{
    const int b = blockIdx.y;

    __shared__ int   sgl[64];
    __shared__ f32x4 tbl[64];             // (m0,m1,s0,s1) per label (C==2)

    for (int i = threadIdx.x; i < L; i += blockDim.x) {
        sgl[i] = gen_labels[i];
        const float* mp = means + ((long long)b * L + i) * 2;
        const float* sp = stds  + ((long long)b * L + i) * 2;
        f32x4 t; t.x = mp[0]; t.y = mp[1]; t.z = sp[0]; t.w = sp[1];
        tbl[i] = t;
    }
    __syncthreads();

    const int g0 = sgl[0];
    bool ar = true;
    for (int i = 1; i < L; ++i) ar = ar && (sgl[i] == g0 + i);

    const int NV4 = V >> 2;
    const unsigned uL = (unsigned)L;
    const int base = blockIdx.x * (blockDim.x * TGROUPS) + threadIdx.x;

    const int4*  lab4 = (const int4*)(labels + (long long)b * V);
    const f32x4* nz0  = (const f32x4*)(noise + (long long)(b * C + 0) * V);
    const f32x4* nz1  = (const f32x4*)(noise + (long long)(b * C + 1) * V);
    f32x4* o0 = (f32x4*)(out + (long long)(b * C + 0) * V);
    f32x4* o1 = (f32x4*)(out + (long long)(b * C + 1) * V);

    if (ar) {
        // Issue ALL global loads first: 4 int4 + 8 float4 = 12 VMEM in flight.
        int4  la[TGROUPS];
        f32x4 na[TGROUPS], nb[TGROUPS];
#pragma unroll
        for (int k = 0; k < TGROUPS; ++k) la[k] = lab4[base + k * 256];
#pragma unroll
        for (int k = 0; k < TGROUPS; ++k) na[k] = nz0[base + k * 256];
#pragma unroll
        for (int k = 0; k < TGROUPS; ++k) nb[k] = nz1[base + k * 256];

#pragma unroll
        for (int k = 0; k < TGROUPS; ++k) {
            const int lv[4] = {la[k].x, la[k].y, la[k].z, la[k].w};
            f32x4 t[4];
            bool  val[4];
#pragma unroll
            for (int j = 0; j < 4; ++j) {
                const unsigned d = (unsigned)(lv[j] - g0);
                val[j] = d < uL;
                const unsigned ix = val[j] ? d : 0u;
                t[j] = tbl[ix];                       // ds_read_b128
            }
            f32x4 oa, ob;
            oa.x = val[0] ? fmaf(t[0].z, na[k].x, t[0].x) : 0.f;
            oa.y = val[1] ? fmaf(t[1].z, na[k].y, t[1].x) : 0.f;
            oa.z = val[2] ? fmaf(t[2].z, na[k].z, t[2].x) : 0.f;
            oa.w = val[3] ? fmaf(t[3].z, na[k].w, t[3].x) : 0.f;
            ob.x = val[0] ? fmaf(t[0].w, nb[k].x, t[0].y) : 0.f;
            ob.y = val[1] ? fmaf(t[1].w, nb[k].y, t[1].y) : 0.f;
            ob.z = val[2] ? fmaf(t[2].w, nb[k].z, t[2].y) : 0.f;
            ob.w = val[3] ? fmaf(t[3].w, nb[k].w, t[3].y) : 0.f;
            __builtin_nontemporal_store(oa, &o0[base + k * 256]);
            __builtin_nontemporal_store(ob, &o1[base + k * 256]);
        }
    } else {
        // Generic: binary search per label (still exact-fit addressing).
#pragma unroll
        for (int k = 0; k < TGROUPS; ++k) {
            const int i0 = base + k * 256;
            const int4 la = lab4[i0];
            const int lv[4] = {la.x, la.y, la.z, la.w};
            f32x4 t[4]; bool val[4];
#pragma unroll
            for (int j = 0; j < 4; ++j) {
                int lo = searchsorted_left(sgl, L, lv[j]);
                int ix = lo < (L - 1) ? lo : (L - 1);
                val[j] = (sgl[ix] == lv[j]);
                t[j] = tbl[ix];
            }
            const f32x4 na = nz0[i0];
            const f32x4 nb = nz1[i0];
            f32x4 oa, ob;
            oa.x = val[0] ? fmaf(t[0].z, na.x, t[0].x) : 0.f;
            oa.y = val[1] ? fmaf(t[1].z, na.y, t[1].x) : 0.f;
            oa.z = val[2] ? fmaf(t[2].z, na.z, t[2].x) : 0.f;
            oa.w = val[3] ? fmaf(t[3].z, na.w, t[3].x) : 0.f;
            ob.x = val[0] ? fmaf(t[0].w, nb.x, t[0].y) : 0.f;
            ob.y = val[1] ? fmaf(t[1].w, nb.y, t[1].y) : 0.f;
            ob.z = val[2] ? fmaf(t[2].w, nb.z, t[2].y) : 0.f;
            ob.w = val[3] ? fmaf(t[3].w, nb.w, t[3].y) : 0.f;
            __builtin_nontemporal_store(oa, &o0[i0]);
            __builtin_nontemporal_store(ob, &o1[i0]);
        }
    }
}

// ---------------- flexible fallback (any shape, any C) -----------------------
__global__ __launch_bounds__(256) void gmm_flex_kernel(
    const int*   __restrict__ labels,
    const float* __restrict__ means,
    const float* __restrict__ stds,
    const float* __restrict__ noise,
    const int*   __restrict__ gen_labels,
    float*       __restrict__ out,
    int B, int L, int C, int V)
{
    extern __shared__ char smem_raw[];
    int*   sgl = (int*)smem_raw;              // [L]
    float* smn = (float*)(sgl + ((L + 3) & ~3));
    float* ssd = smn + L * C;

    const int b = blockIdx.y;
    const long long tb = (long long)b * L * C;
    for (int i = threadIdx.x; i < L; i += blockDim.x) sgl[i] = gen_labels[i];
    for (int i = threadIdx.x; i < L * C; i += blockDim.x) {
        smn[i] = means[tb + i]; ssd[i] = stds[tb + i];
    }
    __syncthreads();

    const int NV4 = V >> 2;
    const int4* lab4 = (const int4*)(labels + (long long)b * V);
    const int stride = gridDim.x * blockDim.x;

    for (int i0 = blockIdx.x * blockDim.x + threadIdx.x; i0 < NV4; i0 += stride) {
        const int4 la = lab4[i0];
        const int lv[4] = {la.x, la.y, la.z, la.w};
        int idx[4]; bool val[4];
#pragma unroll
        for (int j = 0; j < 4; ++j) {
            int lo = searchsorted_left(sgl, L, lv[j]);
            int ix = lo < (L - 1) ? lo : (L - 1);
            idx[j] = ix;
            val[j] = (sgl[ix] == lv[j]);
        }
        for (int c = 0; c < C; ++c) {
            const long long plane = ((long long)(b * C + c) * V) >> 2;
            const float4 nzv = ((const float4*)noise)[plane + i0];
            const float nv[4] = {nzv.x, nzv.y, nzv.z, nzv.w};
            f32x4 o;
#pragma unroll
            for (int j = 0; j < 4; ++j) {
                const int t = idx[j] * C + c;
                float r = val[j] ? fmaf(ssd[t], nv[j], smn[t]) : 0.f;
                if (j == 0) o.x = r; else if (j == 1) o.y = r;
                else if (j == 2) o.z = r; else o.w = r;
            }
            __builtin_nontemporal_store(o, (f32x4*)out + plane + i0);
        }
    }
}

// Scalar tail for V % 4 != 0 (not hit for 160^3).
__global__ void gmm_tail_kernel(
    const int*   __restrict__ labels,
    const float* __restrict__ means,
    const float* __restrict__ stds,
    const float* __restrict__ noise,
    const int*   __restrict__ gen_labels,
    float*       __restrict__ out,
    int B, int L, int C, int V, int vstart)
{
    const int tail   = V - vstart;
    const int total  = B * tail;
    const int stride = gridDim.x * blockDim.x;
    for (int g = blockIdx.x * blockDim.x + threadIdx.x; g < total; g += stride) {
        const int b = g / tail;
        const int v = vstart + (g - b * tail);
        const int labv = labels[(long long)b * V + v];
        int lo = 0, hi = L;
        while (lo < hi) { int mid = (lo + hi) >> 1; if (gen_labels[mid] < labv) lo = mid + 1; else hi = mid; }
        int ix = lo < (L - 1) ? lo : (L - 1);
        bool valid = (gen_labels[ix] == labv);
        for (int c = 0; c < C; ++c) {
            const int t = (b * L + ix) * C + c;
            const long long p = (long long)(b * C + c) * V + v;
            out[p] = valid ? fmaf(stds[t], noise[p], means[t]) : 0.0f;
        }
    }
}

extern "C" void kernel_launch(void* const* d_in, const int* in_sizes, int n_in,
                              void* d_out, int out_size, void* d_ws, size_t ws_size,
                              hipStream_t stream) {
    const int*   labels = (const int*)  d_in[0];
    const float* means  = (const float*)d_in[1];
    const float* stds   = (const float*)d_in[2];
    const float* noise  = (const float*)d_in[3];
    const int*   gl     = (const int*)  d_in[4];
    float*       out    = (float*)      d_out;

    const int L = in_sizes[4];                 // 20
    const int C = in_sizes[3] / in_sizes[0];   // 2
    const int B = in_sizes[1] / (L * C);       // 2
    const int V = in_sizes[0] / B;             // 160^3

    const int NV4 = V >> 2;
    const int block = 256;
    const int per_block = block * TGROUPS;

    if (C == 2 && L <= 64 && (NV4 % per_block) == 0) {
        dim3 grid(NV4 / per_block, B);
        gmm_exact_kernel<<<grid, block, 0, stream>>>(
            labels, means, stds, noise, gl, out, L, C, V);
    } else {
        int gx = (NV4 + block - 1) / block;
        if (gx > 2048) gx = 2048;
        if (gx < 1) gx = 1;
        dim3 grid(gx, B);
        size_t smem = (size_t)((L + 3) & ~3) * sizeof(int) +
                      2ull * L * C * sizeof(float);
        gmm_flex_kernel<<<grid, block, smem, stream>>>(
            labels, means, stds, noise, gl, out, B, L, C, V);
    }

    const int vstart = NV4 << 2;
    if (vstart < V) {
        const int tail_total = B * (V - vstart);
        int tgrid = (tail_total + block - 1) / block;
        if (tgrid > 256) tgrid = 256;
        gmm_tail_kernel<<<tgrid, block, 0, stream>>>(
            labels, means, stds, noise, gl, out, B, L, C, V, vstart);
    }
}